// Round 1
// baseline (1447.851 us; speedup 1.0000x reference)
//
#include <hip/hip_runtime.h>

// ProdAttention: LN -> QKV proj -> per-head top-32 of q.k^T (softmax is
// monotone => select on raw sim; scale>0 => skip scaling) -> unweighted
// gather-sum of selected v rows -> global minmax-normalize + exp ->
// transpose -> output proj + bias.  All fp32 (selection is discrete; bf16
// sim errors ~0.006 vs order-stat gaps ~0.014 would flip top-k members).

#define LN_EPS 1e-5f
static constexpr size_t SZ = 4096ull * 1024ull;  // per-buffer element count

// ---------------- float <-> order-preserving key helpers ----------------
__device__ __forceinline__ unsigned fkey(float f) {
  unsigned u = __float_as_uint(f);
  return ((int)u < 0) ? ~u : (u | 0x80000000u);  // monotone: f1<f2 <=> key1<key2
}
__device__ __forceinline__ int enc_i(float f) {  // signed-int monotone encode
  int i = __float_as_int(f);
  return i >= 0 ? i : (i ^ 0x7fffffff);
}
__device__ __forceinline__ float dec_i(int e) {
  return __int_as_float(e >= 0 ? e : (e ^ 0x7fffffff));
}

// ---------------- K1: LayerNorm ----------------
__global__ __launch_bounds__(256)
void ln_kernel(const float* __restrict__ x, const float* __restrict__ gamma,
               const float* __restrict__ beta, float* __restrict__ xn) {
  __shared__ float red[8];
  int row = blockIdx.x, t = threadIdx.x;
  const float4* xr = (const float4*)(x + (size_t)row * 1024);
  float4 v = xr[t];
  float s  = v.x + v.y + v.z + v.w;
  float s2 = v.x*v.x + v.y*v.y + v.z*v.z + v.w*v.w;
  #pragma unroll
  for (int o = 32; o >= 1; o >>= 1) {
    s  += __shfl_xor(s,  o, 64);
    s2 += __shfl_xor(s2, o, 64);
  }
  int w = t >> 6, l = t & 63;
  if (l == 0) { red[w*2] = s; red[w*2+1] = s2; }
  __syncthreads();
  float S  = red[0] + red[2] + red[4] + red[6];
  float S2 = red[1] + red[3] + red[5] + red[7];
  float mu  = S * (1.0f/1024.0f);
  float var = S2 * (1.0f/1024.0f) - mu*mu;
  float r = rsqrtf(var + LN_EPS);
  float4 g  = ((const float4*)gamma)[t];
  float4 bb = ((const float4*)beta)[t];
  float4 o4;
  o4.x = (v.x - mu) * r * g.x + bb.x;
  o4.y = (v.y - mu) * r * g.y + bb.y;
  o4.z = (v.z - mu) * r * g.z + bb.z;
  o4.w = (v.w - mu) * r * g.w + bb.w;
  ((float4*)(xn + (size_t)row * 1024))[t] = o4;
}

// ---------------- K2/K5: fp32 NT GEMM, 128x128 tile, 8x8 micro ----------------
// C[t][e] = sum_d A[t*1024+d] * B[e*1024+d]
// MODE 0: scatter qkv -> q/k/v in [b*h][n][d] layout.  MODE 1: C0 = acc + bias.
template<int MODE>
__global__ __launch_bounds__(256)
void gemm_nt(const float* __restrict__ A, const float* __restrict__ B,
             const float* __restrict__ bias, float* __restrict__ C0,
             float* __restrict__ C1, float* __restrict__ C2) {
  __shared__ float a_lds[128][36];
  __shared__ float b_lds[128][36];
  const int K = 1024;
  int tid = threadIdx.x;
  int tx = tid & 15, ty = tid >> 4;
  int m0 = blockIdx.y * 128, n0 = blockIdx.x * 128;
  float acc[8][8] = {};
  for (int kt = 0; kt < K; kt += 32) {
    __syncthreads();
    #pragma unroll
    for (int it = 0; it < 4; ++it) {
      int idx = it * 256 + tid;
      int r = idx >> 3, c = idx & 7;
      *(float4*)&a_lds[r][c*4] = *(const float4*)&A[(size_t)(m0 + r) * K + kt + c*4];
      *(float4*)&b_lds[r][c*4] = *(const float4*)&B[(size_t)(n0 + r) * K + kt + c*4];
    }
    __syncthreads();
    #pragma unroll
    for (int kk = 0; kk < 32; kk += 4) {
      float4 af[8], bf[8];
      #pragma unroll
      for (int u = 0; u < 8; ++u) af[u] = *(float4*)&a_lds[u*16 + ty][kk];
      #pragma unroll
      for (int vv = 0; vv < 8; ++vv) bf[vv] = *(float4*)&b_lds[vv*16 + tx][kk];
      #pragma unroll
      for (int u = 0; u < 8; ++u)
        #pragma unroll
        for (int vv = 0; vv < 8; ++vv) {
          acc[u][vv] += af[u].x * bf[vv].x;
          acc[u][vv] += af[u].y * bf[vv].y;
          acc[u][vv] += af[u].z * bf[vv].z;
          acc[u][vv] += af[u].w * bf[vv].w;
        }
    }
  }
  #pragma unroll
  for (int u = 0; u < 8; ++u) {
    int row = m0 + u*16 + ty;
    #pragma unroll
    for (int vv = 0; vv < 8; ++vv) {
      int col = n0 + vv*16 + tx;
      float val = acc[u][vv];
      if (MODE == 0) {
        int which = col >> 10, h = (col >> 6) & 15, dd = col & 63;
        int b = row >> 10, i = row & 1023;
        size_t dst = ((size_t)(b*16 + h) << 16) + ((size_t)i << 6) + dd;
        float* D = (which == 0) ? C0 : ((which == 1) ? C1 : C2);
        D[dst] = val;
      } else {
        C0[(size_t)row * 1024 + col] = val + bias[col];
      }
    }
  }
}

// ---------------- K3 init ----------------
__global__ void init_kernel(int* minmax) {
  minmax[0] = 0x7fffffff;          // running min (encoded)
  minmax[1] = (int)0x80000000;     // running max (encoded)
}

// ---------------- K3: fused sim + top-32 select + v gather-sum ----------------
// One block = 16 q-rows of one head (4 rows per wave).  K staged in LDS in
// 128-row tiles; each lane accumulates sims for j == lane (mod 64), 16 slots
// per row held in registers.  Per-wave 32-bit binary search over
// order-preserving keys finds the exact 32nd-largest key; ballot compaction
// with lower-index tie-break yields exactly the reference top-k SET.
__global__ __launch_bounds__(256)
void attn_kernel(const float* __restrict__ qg, const float* __restrict__ kg,
                 const float* __restrict__ vg, float* __restrict__ xsum,
                 int* __restrict__ minmax) {
  __shared__ float klds[128][68];   // +4 pad keeps b128 reads off a single bank column
  __shared__ float qlds[16][64];
  __shared__ int sel[4][32];
  int bh = blockIdx.x >> 6, grp = blockIdx.x & 63;
  int tid = threadIdx.x, w = tid >> 6, l = tid & 63;
  size_t hb = (size_t)bh << 16;     // head base (65536 elements per head)

  ((float4*)qlds)[tid] = ((const float4*)(qg + hb + ((size_t)grp << 10)))[tid];

  float sim[4][16];
  #pragma unroll
  for (int i = 0; i < 4; ++i)
    #pragma unroll
    for (int s = 0; s < 16; ++s) sim[i][s] = 0.0f;

  for (int t = 0; t < 8; ++t) {
    __syncthreads();
    const float4* src = (const float4*)(kg + hb + ((size_t)t << 13));
    #pragma unroll
    for (int m = 0; m < 8; ++m) {
      int idx = m * 256 + tid;       // 2048 float4 = 128 rows x 64
      int j = idx >> 4, c = idx & 15;
      *(float4*)&klds[j][c*4] = src[idx];
    }
    __syncthreads();
    #pragma unroll
    for (int kk = 0; kk < 64; kk += 4) {
      float4 qa[4], kb[2];
      #pragma unroll
      for (int i = 0; i < 4; ++i) qa[i] = *(float4*)&qlds[w*4 + i][kk];
      #pragma unroll
      for (int jj = 0; jj < 2; ++jj) kb[jj] = *(float4*)&klds[jj*64 + l][kk];
      #pragma unroll
      for (int i = 0; i < 4; ++i)
        #pragma unroll
        for (int jj = 0; jj < 2; ++jj) {
          sim[i][t*2 + jj] += qa[i].x * kb[jj].x;
          sim[i][t*2 + jj] += qa[i].y * kb[jj].y;
          sim[i][t*2 + jj] += qa[i].z * kb[jj].z;
          sim[i][t*2 + jj] += qa[i].w * kb[jj].w;
        }
    }
  }

  float mn = 3.4e38f, mx = -3.4e38f;
  int i_base = grp * 16 + w * 4;
  const float* vb = vg + hb;
  unsigned long long below = (1ull << l) - 1ull;

  #pragma unroll
  for (int r = 0; r < 4; ++r) {
    unsigned ku[16];
    #pragma unroll
    for (int s = 0; s < 16; ++s) ku[s] = fkey(sim[r][s]);

    // exact 32nd-largest key via bitwise binary search (wave-local)
    unsigned cur = 0u;
    for (int bit = 31; bit >= 0; --bit) {
      unsigned T = cur | (1u << bit);
      int c = 0;
      #pragma unroll
      for (int s = 0; s < 16; ++s) c += (ku[s] >= T) ? 1 : 0;
      #pragma unroll
      for (int o = 32; o >= 1; o >>= 1) c += __shfl_xor(c, o, 64);
      if (c >= 32) cur = T;
    }

    int g = 0;
    #pragma unroll
    for (int s = 0; s < 16; ++s) g += __popcll(__ballot(ku[s] > cur));
    int need = 32 - g;  // equals to take, lowest j first (jax tie-break)

    int base = 0, eqb = 0;
    #pragma unroll
    for (int s = 0; s < 16; ++s) {
      bool gt = ku[s] > cur;
      bool eq = ku[s] == cur;
      unsigned long long meq = __ballot(eq);
      int eqr = eqb + __popcll(meq & below);
      bool take = gt || (eq && (eqr < need));
      unsigned long long mtk = __ballot(take);
      if (take) sel[w][base + __popcll(mtk & below)] = s*64 + l;
      base += __popcll(mtk);
      eqb  += __popcll(meq);
    }

    // unweighted sum of the 32 selected v rows; lane l = feature dd
    float acc = 0.0f;
    #pragma unroll
    for (int s2 = 0; s2 < 32; ++s2) {
      int j = sel[w][s2];
      acc += vb[((size_t)j << 6) + l];
    }
    xsum[hb + ((size_t)(i_base + r) << 6) + l] = acc;
    mn = fminf(mn, acc);
    mx = fmaxf(mx, acc);
  }

  #pragma unroll
  for (int o = 32; o >= 1; o >>= 1) {
    mn = fminf(mn, __shfl_xor(mn, o, 64));
    mx = fmaxf(mx, __shfl_xor(mx, o, 64));
  }
  if (l == 0) {
    atomicMin(minmax,     enc_i(mn));
    atomicMax(minmax + 1, enc_i(mx));
  }
}

// ---------------- K4: minmax-normalize + exp + head->token transpose ----------------
__global__ __launch_bounds__(256)
void fin_kernel(const float* __restrict__ xsum, const int* __restrict__ minmax,
                float* __restrict__ outt) {
  int idx = blockIdx.x * 256 + threadIdx.x;  // float4 index, 1048576 total
  float mn = dec_i(minmax[0]);
  float mx = dec_i(minmax[1]);
  float inv = 1.0f / (mx - mn);
  float4 xv = ((const float4*)xsum)[idx];
  float4 o;
  o.x = expf((xv.x - mn) * inv);
  o.y = expf((xv.y - mn) * inv);
  o.z = expf((xv.z - mn) * inv);
  o.w = expf((xv.w - mn) * inv);
  int e0 = idx << 2;
  int bh = e0 >> 16, i = (e0 >> 6) & 1023, dd = e0 & 63;
  int b = bh >> 4, h = bh & 15;
  size_t oe = ((size_t)(b * 1024 + i) << 10) + (h << 6) + dd;
  ((float4*)outt)[oe >> 2] = o;
}

// ---------------- launch ----------------
extern "C" void kernel_launch(void* const* d_in, const int* in_sizes, int n_in,
                              void* d_out, int out_size, void* d_ws, size_t ws_size,
                              hipStream_t stream) {
  const float* x     = (const float*)d_in[0];
  const float* gamma = (const float*)d_in[1];
  const float* beta  = (const float*)d_in[2];
  const float* w_qkv = (const float*)d_in[3];
  const float* w_out = (const float*)d_in[4];
  const float* b_out = (const float*)d_in[5];

  float* ws = (float*)d_ws;
  float* xn = ws;                    // reused as outt after K2 consumes it
  float* q  = ws + SZ;
  float* k  = ws + 2*SZ;
  float* v  = ws + 3*SZ;
  float* xs = ws + 4*SZ;
  int* minmax = (int*)(ws + 5*SZ);
  float* outt = xn;

  ln_kernel<<<4096, 256, 0, stream>>>(x, gamma, beta, xn);
  gemm_nt<0><<<dim3(24, 32), 256, 0, stream>>>(xn, w_qkv, nullptr, q, k, v);
  init_kernel<<<1, 1, 0, stream>>>(minmax);
  attn_kernel<<<4096, 256, 0, stream>>>(q, k, v, xs, minmax);
  fin_kernel<<<4096, 256, 0, stream>>>(xs, minmax, outt);
  gemm_nt<1><<<dim3(8, 32), 256, 0, stream>>>(outt, w_out, b_out, (float*)d_out,
                                              nullptr, nullptr);
}

// Round 3
// 890.047 us; speedup vs baseline: 1.6267x; 1.6267x over previous
//
#include <hip/hip_runtime.h>

// ProdAttention: LN -> QKV proj -> per-head top-32 of q.k^T (softmax monotone
// => select on raw sim) -> unweighted gather-sum of selected v rows -> global
// minmax-normalize + exp -> transpose -> output proj + bias.
// GEMMs use f16 hi/lo-split MFMA (3 terms, ~fp32 precision: dropped lo*lo ~2^-24).
// Selection stays fp32-exact (discrete top-k; precision anchors absmax).

#define LN_EPS 1e-5f
static constexpr size_t SZ = 4096ull * 1024ull;

using half8   = __attribute__((ext_vector_type(8))) _Float16;
using half4   = __attribute__((ext_vector_type(4))) _Float16;
using float4v = __attribute__((ext_vector_type(4))) float;

__device__ __forceinline__ void gload_lds16(const void* g, void* l) {
  __builtin_amdgcn_global_load_lds(
      (const __attribute__((address_space(1))) void*)g,
      (__attribute__((address_space(3))) void*)l, 16, 0, 0);
}
__device__ __forceinline__ float4v mfma16(half8 a, half8 b, float4v c) {
  return __builtin_amdgcn_mfma_f32_16x16x32_f16(a, b, c, 0, 0, 0);
}
struct HL { _Float16 h, l; };
__device__ __forceinline__ HL split2(float x) {
  _Float16 h = (_Float16)x;
  return { h, (_Float16)(x - (float)h) };
}

// ---------------- order-preserving key helpers ----------------
__device__ __forceinline__ unsigned fkey(float f) {
  unsigned u = __float_as_uint(f);
  return ((int)u < 0) ? ~u : (u | 0x80000000u);
}
__device__ __forceinline__ int enc_i(float f) {
  int i = __float_as_int(f);
  return i >= 0 ? i : (i ^ 0x7fffffff);
}
__device__ __forceinline__ float dec_i(int e) {
  return __int_as_float(e >= 0 ? e : (e ^ 0x7fffffff));
}

// ---------------- K1: LayerNorm -> f16 hi/lo planes ----------------
__global__ __launch_bounds__(256)
void ln_kernel(const float* __restrict__ x, const float* __restrict__ gamma,
               const float* __restrict__ beta,
               _Float16* __restrict__ xh, _Float16* __restrict__ xl) {
  __shared__ float red[8];
  int row = blockIdx.x, t = threadIdx.x;
  const float4* xr = (const float4*)(x + (size_t)row * 1024);
  float4 v = xr[t];
  float s  = v.x + v.y + v.z + v.w;
  float s2 = v.x*v.x + v.y*v.y + v.z*v.z + v.w*v.w;
  #pragma unroll
  for (int o = 32; o >= 1; o >>= 1) {
    s  += __shfl_xor(s,  o, 64);
    s2 += __shfl_xor(s2, o, 64);
  }
  int w = t >> 6, l = t & 63;
  if (l == 0) { red[w*2] = s; red[w*2+1] = s2; }
  __syncthreads();
  float S  = red[0] + red[2] + red[4] + red[6];
  float S2 = red[1] + red[3] + red[5] + red[7];
  float mu  = S * (1.0f/1024.0f);
  float var = S2 * (1.0f/1024.0f) - mu*mu;
  float r = rsqrtf(var + LN_EPS);
  float4 g  = ((const float4*)gamma)[t];
  float4 bb = ((const float4*)beta)[t];
  float o0 = (v.x - mu) * r * g.x + bb.x;
  float o1 = (v.y - mu) * r * g.y + bb.y;
  float o2 = (v.z - mu) * r * g.z + bb.z;
  float o3 = (v.w - mu) * r * g.w + bb.w;
  HL r0 = split2(o0), r1 = split2(o1), r2 = split2(o2), r3 = split2(o3);
  half4 hh = { r0.h, r1.h, r2.h, r3.h };
  half4 ll = { r0.l, r1.l, r2.l, r3.l };
  size_t e = (size_t)row * 1024 + t*4;
  *(half4*)(xh + e) = hh;
  *(half4*)(xl + e) = ll;
}

// ---------------- K1b: weight fp32 -> f16 hi/lo planes ----------------
__global__ __launch_bounds__(256)
void cvt_kernel(const float* __restrict__ wqkv, const float* __restrict__ wout,
                _Float16* __restrict__ wqh, _Float16* __restrict__ wql,
                _Float16* __restrict__ woh, _Float16* __restrict__ wol) {
  size_t i4 = (size_t)blockIdx.x * 256 + threadIdx.x;   // float4 index, 1M total
  const float* src; _Float16 *dh, *dl; size_t off;
  if (i4 < 786432) { src = wqkv; dh = wqh; dl = wql; off = i4; }
  else             { src = wout; dh = woh; dl = wol; off = i4 - 786432; }
  float4 v = ((const float4*)src)[off];
  HL r0 = split2(v.x), r1 = split2(v.y), r2 = split2(v.z), r3 = split2(v.w);
  half4 hh = { r0.h, r1.h, r2.h, r3.h };
  half4 ll = { r0.l, r1.l, r2.l, r3.l };
  ((half4*)dh)[off] = hh;
  ((half4*)dl)[off] = ll;
}

// ---------------- K2/K5: f16-split MFMA NT GEMM, 128x128 tile ----------------
// C[m][n] = sum_k A[m][k]*B[n][k], A = Ah+Al, B = Bh+Bl (3 MFMA terms).
// MODE 0: scatter qkv -> q/k/v [b*h][n][d].  MODE 1: C0 = acc + bias.
template<int MODE>
__global__ __launch_bounds__(256)
void gemm_f16split(const _Float16* __restrict__ Ah, const _Float16* __restrict__ Al,
                   const _Float16* __restrict__ Bh, const _Float16* __restrict__ Bl,
                   const float* __restrict__ bias, float* __restrict__ C0,
                   float* __restrict__ C1, float* __restrict__ C2) {
  __shared__ __align__(16) _Float16 lds[4 * 128 * 32];  // Ah | Al | Bh | Bl tiles
  const int K = 1024;
  int tid = threadIdx.x, w = tid >> 6, l = tid & 63;
  int m0 = blockIdx.y * 128, n0 = blockIdx.x * 128;
  int wm = (w >> 1) * 64, wn = (w & 1) * 64;

  // wave w stages plane w (128 rows x 32 halves = 8KB, 8 x 16B-per-lane)
  const _Float16* src = (w == 0) ? Ah : (w == 1) ? Al : (w == 2) ? Bh : Bl;
  int rowbase = (w < 2) ? m0 : n0;
  _Float16* dst = lds + (size_t)w * 4096;
  int sr = l >> 2, sc = l & 3;

  float4v acc[4][4];
  #pragma unroll
  for (int u = 0; u < 4; ++u)
    #pragma unroll
    for (int vv = 0; vv < 4; ++vv) acc[u][vv] = (float4v){0.f, 0.f, 0.f, 0.f};

  int quad = l >> 4, lo16 = l & 15;
  for (int kt = 0; kt < K; kt += 32) {
    __syncthreads();
    #pragma unroll
    for (int i = 0; i < 8; ++i) {
      int row = i * 16 + sr;
      gload_lds16(src + (size_t)(rowbase + row) * K + kt + sc * 8,
                  dst + row * 32 + sc * 8);
    }
    __syncthreads();
    half8 ah[4], al[4], bh[4], bl[4];
    #pragma unroll
    for (int u = 0; u < 4; ++u) {
      int mrow = wm + u * 16 + lo16;
      int nrow = wn + u * 16 + lo16;
      ah[u] = *(const half8*)&lds[        (size_t)mrow * 32 + quad * 8];
      al[u] = *(const half8*)&lds[ 4096 + (size_t)mrow * 32 + quad * 8];
      bh[u] = *(const half8*)&lds[ 8192 + (size_t)nrow * 32 + quad * 8];
      bl[u] = *(const half8*)&lds[12288 + (size_t)nrow * 32 + quad * 8];
    }
    #pragma unroll
    for (int u = 0; u < 4; ++u)
      #pragma unroll
      for (int vv = 0; vv < 4; ++vv) {
        acc[u][vv] = mfma16(ah[u], bh[vv], acc[u][vv]);
        acc[u][vv] = mfma16(ah[u], bl[vv], acc[u][vv]);
        acc[u][vv] = mfma16(al[u], bh[vv], acc[u][vv]);
      }
  }

  // epilogue: C row = m index ((lane>>4)*4+reg), col = n index (lane&15)
  #pragma unroll
  for (int u = 0; u < 4; ++u) {
    #pragma unroll
    for (int vv = 0; vv < 4; ++vv) {
      #pragma unroll
      for (int rg = 0; rg < 4; ++rg) {
        int row = m0 + wm + u * 16 + quad * 4 + rg;
        int col = n0 + wn + vv * 16 + lo16;
        float val = acc[u][vv][rg];
        if (MODE == 0) {
          int which = col >> 10, h = (col >> 6) & 15, dd = col & 63;
          int b = row >> 10, i = row & 1023;
          size_t ds2 = ((size_t)(b * 16 + h) << 16) + ((size_t)i << 6) + dd;
          float* D = (which == 0) ? C0 : ((which == 1) ? C1 : C2);
          D[ds2] = val;
        } else {
          C0[(size_t)row * 1024 + col] = val + bias[col];
        }
      }
    }
  }
}

// ---------------- K3 init ----------------
__global__ void init_kernel(int* minmax) {
  minmax[0] = 0x7fffffff;
  minmax[1] = (int)0x80000000;
}

// ---------------- K3: fused sim + top-32 select + v gather-sum ----------------
__global__ __launch_bounds__(256)
void attn_kernel(const float* __restrict__ qg, const float* __restrict__ kg,
                 const float* __restrict__ vg, float* __restrict__ xsum,
                 int* __restrict__ minmax) {
  __shared__ float klds[128][68];
  __shared__ float qlds[16][64];
  __shared__ int sel[4][32];
  // XCD swizzle: all 64 row-blocks of a head on one XCD (k+v fit 4MB L2)
  int g = blockIdx.x;
  int xcd = g & 7, slot = g >> 3;
  int bh = (slot >> 6) * 8 + xcd, grp = slot & 63;
  int tid = threadIdx.x, w = tid >> 6, l = tid & 63;
  size_t hb = (size_t)bh << 16;

  ((float4*)qlds)[tid] = ((const float4*)(qg + hb + ((size_t)grp << 10)))[tid];

  float sim[4][16];
  #pragma unroll
  for (int i = 0; i < 4; ++i)
    #pragma unroll
    for (int s = 0; s < 16; ++s) sim[i][s] = 0.0f;

  for (int t = 0; t < 8; ++t) {
    __syncthreads();
    const float4* src = (const float4*)(kg + hb + ((size_t)t << 13));
    #pragma unroll
    for (int m = 0; m < 8; ++m) {
      int idx = m * 256 + tid;
      int j = idx >> 4, c = idx & 15;
      *(float4*)&klds[j][c*4] = src[idx];
    }
    __syncthreads();
    #pragma unroll
    for (int kk = 0; kk < 64; kk += 4) {
      float4 qa[4], kb[2];
      #pragma unroll
      for (int i = 0; i < 4; ++i) qa[i] = *(float4*)&qlds[w*4 + i][kk];
      #pragma unroll
      for (int jj = 0; jj < 2; ++jj) kb[jj] = *(float4*)&klds[jj*64 + l][kk];
      #pragma unroll
      for (int i = 0; i < 4; ++i)
        #pragma unroll
        for (int jj = 0; jj < 2; ++jj) {
          sim[i][t*2 + jj] += qa[i].x * kb[jj].x;
          sim[i][t*2 + jj] += qa[i].y * kb[jj].y;
          sim[i][t*2 + jj] += qa[i].z * kb[jj].z;
          sim[i][t*2 + jj] += qa[i].w * kb[jj].w;
        }
    }
  }

  float mn = 3.4e38f, mx = -3.4e38f;
  int i_base = grp * 16 + w * 4;
  const float* vb = vg + hb;
  unsigned long long below = (1ull << l) - 1ull;

  #pragma unroll
  for (int r = 0; r < 4; ++r) {
    unsigned ku[16];
    #pragma unroll
    for (int s = 0; s < 16; ++s) ku[s] = fkey(sim[r][s]);

    // binary search for 32nd-largest key; ballot counts (SALU popcounts),
    // early exit when count(>=T) == 32 exactly (then set = {ku >= cur})
    unsigned cur = 0u;
    bool exact = false;
    for (int bit = 31; bit >= 0; --bit) {
      unsigned T = cur | (1u << bit);
      int c = 0;
      #pragma unroll
      for (int s = 0; s < 16; ++s) c += __popcll(__ballot(ku[s] >= T));
      if (c >= 32) {
        cur = T;
        if (c == 32) { exact = true; break; }
      }
    }
    int need = 9999;
    if (!exact) {
      int gcnt = 0;
      #pragma unroll
      for (int s = 0; s < 16; ++s) gcnt += __popcll(__ballot(ku[s] > cur));
      need = 32 - gcnt;   // ties taken lowest-j first (jax tie-break)
    }

    int base = 0, eqb = 0;
    #pragma unroll
    for (int s = 0; s < 16; ++s) {
      bool gt = ku[s] > cur;
      bool eq = ku[s] == cur;
      unsigned long long meq = __ballot(eq);
      int eqr = eqb + __popcll(meq & below);
      bool take = gt || (eq && (eqr < need));
      unsigned long long mtk = __ballot(take);
      if (take) sel[w][base + __popcll(mtk & below)] = s*64 + l;
      base += __popcll(mtk);
      eqb  += __popcll(meq);
    }

    float acc = 0.0f;
    #pragma unroll
    for (int s2 = 0; s2 < 32; ++s2) {
      int j = sel[w][s2];
      acc += vb[((size_t)j << 6) + l];
    }
    xsum[hb + ((size_t)(i_base + r) << 6) + l] = acc;
    mn = fminf(mn, acc);
    mx = fmaxf(mx, acc);
  }

  #pragma unroll
  for (int o = 32; o >= 1; o >>= 1) {
    mn = fminf(mn, __shfl_xor(mn, o, 64));
    mx = fmaxf(mx, __shfl_xor(mx, o, 64));
  }
  if (l == 0) {
    atomicMin(minmax,     enc_i(mn));
    atomicMax(minmax + 1, enc_i(mx));
  }
}

// ---------------- K4: minmax-norm + exp + transpose -> f16 hi/lo ----------------
__global__ __launch_bounds__(256)
void fin_kernel(const float* __restrict__ xsum, const int* __restrict__ minmax,
                _Float16* __restrict__ oh, _Float16* __restrict__ ol) {
  int idx = blockIdx.x * 256 + threadIdx.x;  // float4 index
  float mn = dec_i(minmax[0]);
  float mx = dec_i(minmax[1]);
  float inv = 1.0f / (mx - mn);
  float4 xv = ((const float4*)xsum)[idx];
  float o0 = expf((xv.x - mn) * inv);
  float o1 = expf((xv.y - mn) * inv);
  float o2 = expf((xv.z - mn) * inv);
  float o3 = expf((xv.w - mn) * inv);
  HL r0 = split2(o0), r1 = split2(o1), r2 = split2(o2), r3 = split2(o3);
  half4 hh = { r0.h, r1.h, r2.h, r3.h };
  half4 ll = { r0.l, r1.l, r2.l, r3.l };
  int e0 = idx << 2;
  int bh = e0 >> 16, i = (e0 >> 6) & 1023, dd = e0 & 63;
  int b = bh >> 4, h = bh & 15;
  size_t oe = ((size_t)(b * 1024 + i) << 10) + (h << 6) + dd;
  *(half4*)(oh + oe) = hh;
  *(half4*)(ol + oe) = ll;
}

// ---------------- launch ----------------
extern "C" void kernel_launch(void* const* d_in, const int* in_sizes, int n_in,
                              void* d_out, int out_size, void* d_ws, size_t ws_size,
                              hipStream_t stream) {
  const float* x     = (const float*)d_in[0];
  const float* gamma = (const float*)d_in[1];
  const float* beta  = (const float*)d_in[2];
  const float* w_qkv = (const float*)d_in[3];
  const float* w_out = (const float*)d_in[4];
  const float* b_out = (const float*)d_in[5];

  float* ws = (float*)d_ws;
  float* q  = ws;                    // [SZ] fp32; reused by outt planes after attn
  float* k  = ws + SZ;               // [SZ]
  float* v  = ws + 2*SZ;             // [SZ]
  float* xs = ws + 3*SZ;             // [SZ] fp32; xh/xl live here before attn
  _Float16* xh = (_Float16*)(ws + 3*SZ);            // SZ halves
  _Float16* xl = (_Float16*)(ws + 3*SZ + SZ/2);
  _Float16* wqh = (_Float16*)(ws + 4*SZ);           // 3M halves
  _Float16* wql = (_Float16*)(ws + 4*SZ + 1572864);
  _Float16* woh = (_Float16*)(ws + 4*SZ + 3145728); // 1M halves
  _Float16* wol = (_Float16*)(ws + 4*SZ + 3670016);
  int* minmax = (int*)(ws + 5*SZ);
  _Float16* oth = (_Float16*)q;                     // after attn: outt hi
  _Float16* otl = (_Float16*)(ws + SZ/2);           // outt lo (still in q slot)

  ln_kernel<<<4096, 256, 0, stream>>>(x, gamma, beta, xh, xl);
  cvt_kernel<<<4096, 256, 0, stream>>>(w_qkv, w_out, wqh, wql, woh, wol);
  gemm_f16split<0><<<dim3(24, 32), 256, 0, stream>>>(xh, xl, wqh, wql, nullptr,
                                                     q, k, v);
  init_kernel<<<1, 1, 0, stream>>>(minmax);
  attn_kernel<<<4096, 256, 0, stream>>>(q, k, v, xs, minmax);
  fin_kernel<<<4096, 256, 0, stream>>>(xs, minmax, oth, otl);
  gemm_f16split<1><<<dim3(8, 32), 256, 0, stream>>>(oth, otl, woh, wol, b_out,
                                                    (float*)d_out, nullptr, nullptr);
}

// Round 4
// 683.482 us; speedup vs baseline: 2.1183x; 1.3022x over previous
//
#include <hip/hip_runtime.h>

// ProdAttention: LN -> QKV proj -> per-head top-32 of q.k^T (softmax monotone
// => select on raw sim) -> unweighted gather-sum of selected v rows -> global
// minmax-normalize + exp -> transpose -> output proj + bias.
// GEMMs: f16 hi/lo-split MFMA (3 terms ~ fp32 precision).  Sim: fp32 VALU,
// streaming kT rows from L1/L2 (no barriers, no K LDS staging).  Selection
// fp32-exact wave ballots (discrete top-k anchors absmax).

#define LN_EPS 1e-5f
static constexpr size_t SZ = 4096ull * 1024ull;

using half8   = __attribute__((ext_vector_type(8))) _Float16;
using half4   = __attribute__((ext_vector_type(4))) _Float16;
using float4v = __attribute__((ext_vector_type(4))) float;

__device__ __forceinline__ void gload_lds16(const void* g, void* l) {
  __builtin_amdgcn_global_load_lds(
      (const __attribute__((address_space(1))) void*)g,
      (__attribute__((address_space(3))) void*)l, 16, 0, 0);
}
__device__ __forceinline__ float4v mfma16(half8 a, half8 b, float4v c) {
  return __builtin_amdgcn_mfma_f32_16x16x32_f16(a, b, c, 0, 0, 0);
}
struct HL { _Float16 h, l; };
__device__ __forceinline__ HL split2(float x) {
  _Float16 h = (_Float16)x;
  return { h, (_Float16)(x - (float)h) };
}

// ---------------- order-preserving key helpers ----------------
__device__ __forceinline__ unsigned fkey(float f) {
  unsigned u = __float_as_uint(f);
  return ((int)u < 0) ? ~u : (u | 0x80000000u);
}
__device__ __forceinline__ int enc_i(float f) {
  int i = __float_as_int(f);
  return i >= 0 ? i : (i ^ 0x7fffffff);
}
__device__ __forceinline__ float dec_i(int e) {
  return __int_as_float(e >= 0 ? e : (e ^ 0x7fffffff));
}

// ---------------- K1: LayerNorm -> f16 hi/lo planes ----------------
__global__ __launch_bounds__(256)
void ln_kernel(const float* __restrict__ x, const float* __restrict__ gamma,
               const float* __restrict__ beta,
               _Float16* __restrict__ xh, _Float16* __restrict__ xl) {
  __shared__ float red[8];
  int row = blockIdx.x, t = threadIdx.x;
  const float4* xr = (const float4*)(x + (size_t)row * 1024);
  float4 v = xr[t];
  float s  = v.x + v.y + v.z + v.w;
  float s2 = v.x*v.x + v.y*v.y + v.z*v.z + v.w*v.w;
  #pragma unroll
  for (int o = 32; o >= 1; o >>= 1) {
    s  += __shfl_xor(s,  o, 64);
    s2 += __shfl_xor(s2, o, 64);
  }
  int w = t >> 6, l = t & 63;
  if (l == 0) { red[w*2] = s; red[w*2+1] = s2; }
  __syncthreads();
  float S  = red[0] + red[2] + red[4] + red[6];
  float S2 = red[1] + red[3] + red[5] + red[7];
  float mu  = S * (1.0f/1024.0f);
  float var = S2 * (1.0f/1024.0f) - mu*mu;
  float r = rsqrtf(var + LN_EPS);
  float4 g  = ((const float4*)gamma)[t];
  float4 bb = ((const float4*)beta)[t];
  float o0 = (v.x - mu) * r * g.x + bb.x;
  float o1 = (v.y - mu) * r * g.y + bb.y;
  float o2 = (v.z - mu) * r * g.z + bb.z;
  float o3 = (v.w - mu) * r * g.w + bb.w;
  HL r0 = split2(o0), r1 = split2(o1), r2 = split2(o2), r3 = split2(o3);
  half4 hh = { r0.h, r1.h, r2.h, r3.h };
  half4 ll = { r0.l, r1.l, r2.l, r3.l };
  size_t e = (size_t)row * 1024 + t*4;
  *(half4*)(xh + e) = hh;
  *(half4*)(xl + e) = ll;
}

// ---------------- K1b: weight fp32 -> f16 hi/lo planes ----------------
__global__ __launch_bounds__(256)
void cvt_kernel(const float* __restrict__ wqkv, const float* __restrict__ wout,
                _Float16* __restrict__ wqh, _Float16* __restrict__ wql,
                _Float16* __restrict__ woh, _Float16* __restrict__ wol) {
  size_t i4 = (size_t)blockIdx.x * 256 + threadIdx.x;   // float4 index, 1M total
  const float* src; _Float16 *dh, *dl; size_t off;
  if (i4 < 786432) { src = wqkv; dh = wqh; dl = wql; off = i4; }
  else             { src = wout; dh = woh; dl = wol; off = i4 - 786432; }
  float4 v = ((const float4*)src)[off];
  HL r0 = split2(v.x), r1 = split2(v.y), r2 = split2(v.z), r3 = split2(v.w);
  half4 hh = { r0.h, r1.h, r2.h, r3.h };
  half4 ll = { r0.l, r1.l, r2.l, r3.l };
  ((half4*)dh)[off] = hh;
  ((half4*)dl)[off] = ll;
}

// ---------------- K2/K5: f16-split MFMA NT GEMM, 128x128 tile ----------------
// C[m][n] = sum_k A[m][k]*B[n][k], A = Ah+Al, B = Bh+Bl (3 MFMA terms).
// MODE 0: scatter qkv -> q[bh][n][d], kT[bh][d][n], v[bh][n][d].
// MODE 1: C0 = acc + bias.
template<int MODE>
__global__ __launch_bounds__(256)
void gemm_f16split(const _Float16* __restrict__ Ah, const _Float16* __restrict__ Al,
                   const _Float16* __restrict__ Bh, const _Float16* __restrict__ Bl,
                   const float* __restrict__ bias, float* __restrict__ C0,
                   float* __restrict__ C1, float* __restrict__ C2) {
  __shared__ __align__(16) _Float16 lds[4 * 128 * 32];  // Ah | Al | Bh | Bl tiles
  const int K = 1024;
  int tid = threadIdx.x, w = tid >> 6, l = tid & 63;
  int m0 = blockIdx.y * 128, n0 = blockIdx.x * 128;
  int wm = (w >> 1) * 64, wn = (w & 1) * 64;

  const _Float16* src = (w == 0) ? Ah : (w == 1) ? Al : (w == 2) ? Bh : Bl;
  int rowbase = (w < 2) ? m0 : n0;
  _Float16* dst = lds + (size_t)w * 4096;
  int sr = l >> 2, sc = l & 3;

  float4v acc[4][4];
  #pragma unroll
  for (int u = 0; u < 4; ++u)
    #pragma unroll
    for (int vv = 0; vv < 4; ++vv) acc[u][vv] = (float4v){0.f, 0.f, 0.f, 0.f};

  int quad = l >> 4, lo16 = l & 15;
  for (int kt = 0; kt < K; kt += 32) {
    __syncthreads();
    #pragma unroll
    for (int i = 0; i < 8; ++i) {
      int row = i * 16 + sr;
      gload_lds16(src + (size_t)(rowbase + row) * K + kt + sc * 8,
                  dst + row * 32 + sc * 8);
    }
    __syncthreads();
    half8 ah[4], al[4], bh[4], bl[4];
    #pragma unroll
    for (int u = 0; u < 4; ++u) {
      int mrow = wm + u * 16 + lo16;
      int nrow = wn + u * 16 + lo16;
      ah[u] = *(const half8*)&lds[        (size_t)mrow * 32 + quad * 8];
      al[u] = *(const half8*)&lds[ 4096 + (size_t)mrow * 32 + quad * 8];
      bh[u] = *(const half8*)&lds[ 8192 + (size_t)nrow * 32 + quad * 8];
      bl[u] = *(const half8*)&lds[12288 + (size_t)nrow * 32 + quad * 8];
    }
    #pragma unroll
    for (int u = 0; u < 4; ++u)
      #pragma unroll
      for (int vv = 0; vv < 4; ++vv) {
        acc[u][vv] = mfma16(ah[u], bh[vv], acc[u][vv]);
        acc[u][vv] = mfma16(ah[u], bl[vv], acc[u][vv]);
        acc[u][vv] = mfma16(al[u], bh[vv], acc[u][vv]);
      }
  }

  // epilogue: C row = m ((lane>>4)*4+reg), col = n (lane&15)
  #pragma unroll
  for (int u = 0; u < 4; ++u) {
    #pragma unroll
    for (int vv = 0; vv < 4; ++vv) {
      #pragma unroll
      for (int rg = 0; rg < 4; ++rg) {
        int row = m0 + wm + u * 16 + quad * 4 + rg;
        int col = n0 + wn + vv * 16 + lo16;
        float val = acc[u][vv][rg];
        if (MODE == 0) {
          int which = col >> 10, h = (col >> 6) & 15, dd = col & 63;
          int b = row >> 10, i = row & 1023;
          size_t hb2 = (size_t)(b * 16 + h) << 16;
          if (which == 0)      C0[hb2 + ((size_t)i << 6) + dd] = val;
          else if (which == 1) C1[hb2 + ((size_t)dd << 10) + i] = val;  // kT
          else                 C2[hb2 + ((size_t)i << 6) + dd] = val;
        } else {
          C0[(size_t)row * 1024 + col] = val + bias[col];
        }
      }
    }
  }
}

// ---------------- K3 init ----------------
__global__ void init_kernel(int* minmax) {
  minmax[0] = 0x7fffffff;
  minmax[1] = (int)0x80000000;
}

// ---------------- K3: sim (kT streaming) + top-32 select + v gather-sum ----
// Block = 16 q-rows of one head; wave = 4 rows.  Lane l holds sims for
// j = s*64+l, s=0..15 (monotone in ballot order => exact jax tie-break).
// kT rows stream from L1/L2 (all waves of a head share the same 4KB row per
// kd step); double-buffered registers; only ONE barrier (q staging).
__global__ __launch_bounds__(256)
void attn_kernel(const float* __restrict__ qg, const float* __restrict__ kT,
                 const float* __restrict__ vg, float* __restrict__ xsum,
                 int* __restrict__ minmax) {
  __shared__ float qlds[16][64];
  __shared__ int sel[4][32];
  // XCD swizzle: all 64 row-blocks of a head on one XCD (kT+v fit 4MB L2)
  int g = blockIdx.x;
  int xcd = g & 7, slot = g >> 3;
  int bh = (slot >> 6) * 8 + xcd, grp = slot & 63;
  int tid = threadIdx.x, w = tid >> 6, l = tid & 63;
  size_t hb = (size_t)bh << 16;

  ((float4*)qlds)[tid] = ((const float4*)(qg + hb + ((size_t)grp << 10)))[tid];
  __syncthreads();

  float sim[4][16];
  #pragma unroll
  for (int i = 0; i < 4; ++i)
    #pragma unroll
    for (int s = 0; s < 16; ++s) sim[i][s] = 0.0f;

  const float* kTh = kT + hb;
  float kb0[16], kb1[16];
  #pragma unroll
  for (int s = 0; s < 16; ++s) kb0[s] = kTh[s*64 + l];

  // NOTE: last iteration prefetches row kd=64 (one row past this head's kT);
  // lands in the v buffer / next head -- allocated, value unused.
  for (int kd = 0; kd < 64; kd += 2) {
    const float* r1 = kTh + (size_t)(kd + 1) * 1024;
    #pragma unroll
    for (int s = 0; s < 16; ++s) kb1[s] = r1[s*64 + l];
    float q0 = qlds[w*4+0][kd], q1 = qlds[w*4+1][kd];
    float q2 = qlds[w*4+2][kd], q3 = qlds[w*4+3][kd];
    #pragma unroll
    for (int s = 0; s < 16; ++s) {
      sim[0][s] += q0 * kb0[s];
      sim[1][s] += q1 * kb0[s];
      sim[2][s] += q2 * kb0[s];
      sim[3][s] += q3 * kb0[s];
    }
    const float* r2 = kTh + (size_t)(kd + 2) * 1024;
    #pragma unroll
    for (int s = 0; s < 16; ++s) kb0[s] = r2[s*64 + l];
    float p0 = qlds[w*4+0][kd+1], p1 = qlds[w*4+1][kd+1];
    float p2 = qlds[w*4+2][kd+1], p3 = qlds[w*4+3][kd+1];
    #pragma unroll
    for (int s = 0; s < 16; ++s) {
      sim[0][s] += p0 * kb1[s];
      sim[1][s] += p1 * kb1[s];
      sim[2][s] += p2 * kb1[s];
      sim[3][s] += p3 * kb1[s];
    }
  }

  float mn = 3.4e38f, mx = -3.4e38f;
  int i_base = grp * 16 + w * 4;
  const float* vb = vg + hb;
  unsigned long long below = (1ull << l) - 1ull;

  #pragma unroll
  for (int r = 0; r < 4; ++r) {
    unsigned ku[16];
    #pragma unroll
    for (int s = 0; s < 16; ++s) ku[s] = fkey(sim[r][s]);

    // binary search for 32nd-largest key; early exit at exact count 32
    unsigned cur = 0u;
    bool exact = false;
    for (int bit = 31; bit >= 0; --bit) {
      unsigned T = cur | (1u << bit);
      int c = 0;
      #pragma unroll
      for (int s = 0; s < 16; ++s) c += __popcll(__ballot(ku[s] >= T));
      if (c >= 32) {
        cur = T;
        if (c == 32) { exact = true; break; }
      }
    }
    int need = 9999;
    if (!exact) {
      int gcnt = 0;
      #pragma unroll
      for (int s = 0; s < 16; ++s) gcnt += __popcll(__ballot(ku[s] > cur));
      need = 32 - gcnt;   // ties taken lowest-j first (jax tie-break)
    }

    int base = 0, eqb = 0;
    #pragma unroll
    for (int s = 0; s < 16; ++s) {
      bool gt = ku[s] > cur;
      bool eq = ku[s] == cur;
      unsigned long long meq = __ballot(eq);
      int eqr = eqb + __popcll(meq & below);
      bool take = gt || (eq && (eqr < need));
      unsigned long long mtk = __ballot(take);
      if (take) sel[w][base + __popcll(mtk & below)] = s*64 + l;
      base += __popcll(mtk);
      eqb  += __popcll(meq);
    }

    float acc = 0.0f;
    #pragma unroll
    for (int s2 = 0; s2 < 32; ++s2) {
      int j = sel[w][s2];
      acc += vb[((size_t)j << 6) + l];
    }
    xsum[hb + ((size_t)(i_base + r) << 6) + l] = acc;
    mn = fminf(mn, acc);
    mx = fmaxf(mx, acc);
  }

  #pragma unroll
  for (int o = 32; o >= 1; o >>= 1) {
    mn = fminf(mn, __shfl_xor(mn, o, 64));
    mx = fmaxf(mx, __shfl_xor(mx, o, 64));
  }
  if (l == 0) {
    atomicMin(minmax,     enc_i(mn));
    atomicMax(minmax + 1, enc_i(mx));
  }
}

// ---------------- K4: minmax-norm + exp + transpose -> f16 hi/lo ----------------
__global__ __launch_bounds__(256)
void fin_kernel(const float* __restrict__ xsum, const int* __restrict__ minmax,
                _Float16* __restrict__ oh, _Float16* __restrict__ ol) {
  int idx = blockIdx.x * 256 + threadIdx.x;  // float4 index
  float mn = dec_i(minmax[0]);
  float mx = dec_i(minmax[1]);
  float inv = 1.0f / (mx - mn);
  float4 xv = ((const float4*)xsum)[idx];
  float o0 = expf((xv.x - mn) * inv);
  float o1 = expf((xv.y - mn) * inv);
  float o2 = expf((xv.z - mn) * inv);
  float o3 = expf((xv.w - mn) * inv);
  HL r0 = split2(o0), r1 = split2(o1), r2 = split2(o2), r3 = split2(o3);
  half4 hh = { r0.h, r1.h, r2.h, r3.h };
  half4 ll = { r0.l, r1.l, r2.l, r3.l };
  int e0 = idx << 2;
  int bh = e0 >> 16, i = (e0 >> 6) & 1023, dd = e0 & 63;
  int b = bh >> 4, h = bh & 15;
  size_t oe = ((size_t)(b * 1024 + i) << 10) + (h << 6) + dd;
  *(half4*)(oh + oe) = hh;
  *(half4*)(ol + oe) = ll;
}

// ---------------- launch ----------------
extern "C" void kernel_launch(void* const* d_in, const int* in_sizes, int n_in,
                              void* d_out, int out_size, void* d_ws, size_t ws_size,
                              hipStream_t stream) {
  const float* x     = (const float*)d_in[0];
  const float* gamma = (const float*)d_in[1];
  const float* beta  = (const float*)d_in[2];
  const float* w_qkv = (const float*)d_in[3];
  const float* w_out = (const float*)d_in[4];
  const float* b_out = (const float*)d_in[5];

  float* ws = (float*)d_ws;
  float* q  = ws;                    // [SZ]; reused as oth/otl after attn
  float* kT = ws + SZ;               // [SZ] k transposed [bh][d][n]
  float* v  = ws + 2*SZ;             // [SZ]
  float* xs = ws + 3*SZ;             // [SZ]; xh/xl live here before attn
  _Float16* xh = (_Float16*)(ws + 3*SZ);            // SZ halves
  _Float16* xl = (_Float16*)(ws + 3*SZ + SZ/2);
  _Float16* wqh = (_Float16*)(ws + 4*SZ);           // 3M halves
  _Float16* wql = (_Float16*)(ws + 4*SZ + 1572864);
  _Float16* woh = (_Float16*)(ws + 4*SZ + 3145728); // 1M halves
  _Float16* wol = (_Float16*)(ws + 4*SZ + 3670016);
  int* minmax = (int*)(ws + 5*SZ);
  _Float16* oth = (_Float16*)q;
  _Float16* otl = (_Float16*)(ws + SZ/2);

  // NOTE: QKV gemm (MODE 0) writes xs slot? No -- it reads xh/xl (ws+3SZ)
  // and writes q/kT/v (ws..ws+3SZ).  xs is written only by attn, after
  // xh/xl are dead.  No overlap hazards.
  ln_kernel<<<4096, 256, 0, stream>>>(x, gamma, beta, xh, xl);
  cvt_kernel<<<4096, 256, 0, stream>>>(w_qkv, w_out, wqh, wql, woh, wol);
  gemm_f16split<0><<<dim3(24, 32), 256, 0, stream>>>(xh, xl, wqh, wql, nullptr,
                                                     q, kT, v);
  init_kernel<<<1, 1, 0, stream>>>(minmax);
  attn_kernel<<<4096, 256, 0, stream>>>(q, kT, v, xs, minmax);
  fin_kernel<<<4096, 256, 0, stream>>>(xs, minmax, oth, otl);
  gemm_f16split<1><<<dim3(8, 32), 256, 0, stream>>>(oth, otl, woh, wol, b_out,
                                                    (float*)d_out, nullptr, nullptr);
}